// Round 13
// baseline (338.450 us; speedup 1.0000x reference)
//
#include <hip/hip_runtime.h>
#include <hip/hip_bf16.h>

#define D 128

typedef __bf16 bf16x8 __attribute__((ext_vector_type(8)));
typedef float floatx4 __attribute__((ext_vector_type(4)));

// ---------------- CSR build ----------------

__global__ void k_count(const int* __restrict__ dst, int E, int* __restrict__ cnt) {
    int e = blockIdx.x * blockDim.x + threadIdx.x;
    if (e < E) atomicAdd(&cnt[dst[e]], 1);
}

__global__ __launch_bounds__(256) void k_scan1(const int* __restrict__ cnt, int n,
                                               int* __restrict__ bsum) {
    int i = blockIdx.x * 256 + threadIdx.x;
    int x = (i < n) ? cnt[i] : 0;
    #pragma unroll
    for (int off = 32; off > 0; off >>= 1) x += __shfl_xor(x, off, 64);
    __shared__ int ws[4];
    if ((threadIdx.x & 63) == 0) ws[threadIdx.x >> 6] = x;
    __syncthreads();
    if (threadIdx.x == 0) bsum[blockIdx.x] = ws[0] + ws[1] + ws[2] + ws[3];
}

// scan3 with scan2 folded in + WINDOW-256 degree sort folded in.
// R12 lesson: a GLOBAL degree sort scatters esrc/row_ptr reads (each ~32B edge
// run pulls a 128B line -> FETCH doubled 22->44MB, agg slower). Window sort
// keeps each node within its 256-node window: esrc span per window ~8KB (fully
// consumed by the same XCD pair -> zero locality cost) while the 8 perm entries
// forming a wave get near-equal degrees (max-of-4-groups ~ mean -> no masked
// gather iterations). Block-local LDS counting sort: no global atomics, no
// extra dispatches.
__global__ __launch_bounds__(256) void k_scan3(const int* __restrict__ cnt,
                                               const int* __restrict__ bsum, int n, int E,
                                               int* __restrict__ row_ptr, int* __restrict__ cursor,
                                               float* __restrict__ dinv,
                                               unsigned short* __restrict__ perm) {
    __shared__ int ws[4];
    __shared__ int hist[64];
    __shared__ int base[64];
    int t = threadIdx.x;
    int lane = t & 63, wid = t >> 6;
    if (t < 64) hist[t] = 0;
    // block base = sum of bsum[0..bid)
    int xb = 0;
    for (int j = t; j < blockIdx.x; j += 256) xb += bsum[j];
    #pragma unroll
    for (int off = 32; off > 0; off >>= 1) xb += __shfl_xor(xb, off, 64);
    if (lane == 0) ws[wid] = xb;
    __syncthreads();
    int o = ws[0] + ws[1] + ws[2] + ws[3];
    __syncthreads();
    // per-element prefix within block
    int i = blockIdx.x * 256 + t;
    int x = (i < n) ? cnt[i] : 0;
    int incl = x;
    #pragma unroll
    for (int off = 1; off < 64; off <<= 1) {
        int y = __shfl_up(incl, off, 64);
        if (lane >= off) incl += y;
    }
    if (lane == 63) ws[wid] = incl;
    __syncthreads();
    for (int w = 0; w < wid; w++) o += ws[w];
    int b = x < 63 ? x : 63;
    int rank = 0;
    if (i < n) {
        int excl = o + incl - x;
        row_ptr[i] = excl;
        cursor[i] = excl;
        dinv[i] = rsqrtf((float)(x + 1));  // +1 self loop
        rank = atomicAdd(&hist[b], 1);     // LDS atomic (window-local)
    }
    __syncthreads();
    if (t == 0) {
        int acc = 0;
        for (int bb = 63; bb >= 0; bb--) {  // descending degree within window
            base[bb] = acc;
            acc += hist[bb];
        }
    }
    __syncthreads();
    if (i < n) perm[blockIdx.x * 256 + base[b] + rank] = (unsigned short)i;
    if (blockIdx.x == 0 && t == 0) row_ptr[n] = E;
}

// XCD-pinned range fill: range = bid & 7 = XCD. Each XCD scans all E but keeps
// only dst in its N/8 range -> esrc window (~200KB) + cursor slice live in ONE
// L2, written back once; atomics XCD-local. (Single-pass variant had 25x write
// amplification: 41MB HBM writes for 1.6MB payload.)
__global__ __launch_bounds__(256) void k_fill(const int* __restrict__ src,
                                              const int* __restrict__ dst, int E,
                                              int* __restrict__ cursor,
                                              unsigned short* __restrict__ esrc, int n) {
    int range = blockIdx.x & 7;          // = XCD
    int rb = blockIdx.x >> 3;            // block index within range
    int nb = gridDim.x >> 3;             // blocks per range
    int rs = (n + 7) >> 3;
    int lo = range * rs, hi = lo + rs;
    int step = nb * 256;
    for (int e = rb * 256 + threadIdx.x; e < E; e += step) {
        int d = dst[e];
        int s = src[e];
        if (d >= lo && d < hi) {
            int p = atomicAdd(&cursor[d], 1);
            esrc[p] = (unsigned short)s;
        }
    }
}

// ---------------- W transpose+bf16 precompute (+ cnt zeroing folded in) ----------------
// blocks 0..2: Wt[n][k] = bf16(W[k][n]); blocks 3..: zero cnt.

__global__ __launch_bounds__(256) void k_prepw(const float* __restrict__ W1,
                                               const float* __restrict__ W2,
                                               const float* __restrict__ W3,
                                               unsigned short* __restrict__ Wt,
                                               int* __restrict__ cnt, int n) {
    int b = blockIdx.x;
    if (b < 3) {
        const float* W = (b == 0) ? W1 : (b == 1) ? W2 : W3;
        unsigned short* o = Wt + b * 16384;
        for (int i = threadIdx.x; i < 16384; i += 256) {
            int k = i >> 7, nn = i & 127;
            __hip_bfloat16 h = __float2bfloat16(W[i]);
            o[nn * 128 + k] = *(unsigned short*)&h;
        }
    } else {
        int i = (b - 3) * 256 + threadIdx.x;
        if (i < n) cnt[i] = 0;
    }
}

// ---------------- MFMA GEMM: hs = bf16( relu_bn(X[m]) @ W * dinv[m] ) ----------
// hs is SLICE-MAJOR: hs_u32[(p * N + node) * 16 + c], p = col-pass 0..3, c 0..15.
// Prologue: finalize BN coefs from 4-way-split raw sums (stats_in), zero next stats buf.

__global__ __launch_bounds__(256) void k_gemm(
    const float* __restrict__ X, const unsigned short* __restrict__ Wt,
    const float* __restrict__ scale, const float* __restrict__ stats_in,
    const float* __restrict__ gamma, const float* __restrict__ beta,
    float* __restrict__ stats_zero,
    unsigned* __restrict__ hs, int n, float invN) {
    __shared__ unsigned short Wl[128 * 128];
    __shared__ float bnl[256];
    int t = threadIdx.x;
    if (stats_in && t < 128) {
        float s = stats_in[t] + stats_in[256 + t] + stats_in[512 + t] + stats_in[768 + t];
        float q = stats_in[128 + t] + stats_in[384 + t] + stats_in[640 + t] + stats_in[896 + t];
        float mean = s * invN;
        float var = q * invN - mean * mean;
        float a = gamma[t] * rsqrtf(var + 1e-5f);
        bnl[t] = a;
        bnl[128 + t] = beta[t] - mean * a;
    }
    if (stats_zero && blockIdx.x == 0) {
        stats_zero[t] = 0.f;
        stats_zero[256 + t] = 0.f;
        stats_zero[512 + t] = 0.f;
        stats_zero[768 + t] = 0.f;
    }
    // stage Wt: 2048 uint4; chunk lc of row nn stored at physical chunk lc^(nn&15)
    {
        const uint4* wg = (const uint4*)Wt;
        uint4* wl4 = (uint4*)Wl;
        #pragma unroll
        for (int j = 0; j < 8; j++) {
            int idx = j * 256 + t;
            int nn = idx >> 4, lc = idx & 15;
            wl4[nn * 16 + (lc ^ (nn & 15))] = wg[idx];
        }
    }
    __syncthreads();

    int l = t & 63, w = t >> 6;
    int lm = l & 15, quad = l >> 4;
    int m = blockIdx.x * 64 + w * 16 + lm;
    int rm = (m < n) ? m : (n - 1);
    const float* xrow = X + (size_t)rm * D;

    floatx4 acc[8];
    #pragma unroll
    for (int nt = 0; nt < 8; nt++) acc[nt] = (floatx4){0.f, 0.f, 0.f, 0.f};

    #pragma unroll
    for (int ks = 0; ks < 4; ks++) {
        int k0 = ks * 32 + quad * 8;
        float4 xa = *(const float4*)(xrow + k0);
        float4 xb = *(const float4*)(xrow + k0 + 4);
        if (stats_in) {
            float4 a0 = *(const float4*)&bnl[k0];
            float4 a1 = *(const float4*)&bnl[k0 + 4];
            float4 c0 = *(const float4*)&bnl[128 + k0];
            float4 c1 = *(const float4*)&bnl[128 + k0 + 4];
            xa.x = fmaxf(xa.x * a0.x + c0.x, 0.f);
            xa.y = fmaxf(xa.y * a0.y + c0.y, 0.f);
            xa.z = fmaxf(xa.z * a0.z + c0.z, 0.f);
            xa.w = fmaxf(xa.w * a0.w + c0.w, 0.f);
            xb.x = fmaxf(xb.x * a1.x + c1.x, 0.f);
            xb.y = fmaxf(xb.y * a1.y + c1.y, 0.f);
            xb.z = fmaxf(xb.z * a1.z + c1.z, 0.f);
            xb.w = fmaxf(xb.w * a1.w + c1.w, 0.f);
        }
        bf16x8 xf;
        xf[0] = (__bf16)xa.x; xf[1] = (__bf16)xa.y;
        xf[2] = (__bf16)xa.z; xf[3] = (__bf16)xa.w;
        xf[4] = (__bf16)xb.x; xf[5] = (__bf16)xb.y;
        xf[6] = (__bf16)xb.z; xf[7] = (__bf16)xb.w;
        int pc = (ks * 4 + quad) ^ lm;
        #pragma unroll
        for (int nt = 0; nt < 8; nt++) {
            const bf16x8 wf = *(const bf16x8*)&Wl[(nt * 16 + lm) * 128 + pc * 8];
            acc[nt] = __builtin_amdgcn_mfma_f32_16x16x32_bf16(wf, xf, acc[nt], 0, 0, 0);
        }
    }

    float s = scale[rm];
    if (m < n) {
        #pragma unroll
        for (int nt = 0; nt < 8; nt++) {
            __hip_bfloat16 h0 = __float2bfloat16(acc[nt][0] * s);
            __hip_bfloat16 h1 = __float2bfloat16(acc[nt][1] * s);
            __hip_bfloat16 h2 = __float2bfloat16(acc[nt][2] * s);
            __hip_bfloat16 h3 = __float2bfloat16(acc[nt][3] * s);
            uint2 uu;
            uu.x = (unsigned)*(unsigned short*)&h0 | ((unsigned)*(unsigned short*)&h1 << 16);
            uu.y = (unsigned)*(unsigned short*)&h2 | ((unsigned)*(unsigned short*)&h3 << 16);
            // slice-major: pass = nt>>1, within-pass u32 col = (nt&1)*8 + quad*2
            *(uint2*)&hs[((size_t)(nt >> 1) * n + m) * 16 + (nt & 1) * 8 + quad * 2] = uu;
        }
    }
}

// ---------------- Column-blocked aggregation (4 passes x 64B slice) ----------
// Proven structure (slice-major hs, XCD-pinned static 1D grid, wide dwordx4
// gathers with 4 lanes/edge, no barriers/queues in loop, 2 nodes per 16-lane
// group) + WINDOW-256 degree-sorted perm: equal-degree nodes share a wave
// (exec-masked gather loop runs max over 4 groups -> max ~ mean) while nodes
// stay within their 256-node window (esrc/row_ptr locality preserved — the
// global sort's 2x FETCH regression, R12, cannot recur by construction).

__device__ inline float2 bf2f(unsigned u) {
    union { unsigned i; float f; } lo, hi;
    lo.i = u << 16;
    hi.i = u & 0xffff0000u;
    float2 r; r.x = lo.f; r.y = hi.f; return r;
}

__device__ __forceinline__ void agg_node_w(
    const unsigned* __restrict__ hsp, const unsigned short* __restrict__ esrc,
    float* __restrict__ out, float (*lsS)[32], float (*lsQ)[32],
    int node, int beg, int end, int e_cur, uint4 sv, float sc,
    float4 bA, float4 bB, int grp, int sub, int qd, int qe, int p, int mode) {
    // self contributes only in edge-slot 0 (summed once after xor-reduce)
    float2 a0 = bf2f(qd == 0 ? sv.x : 0u);
    float2 a1 = bf2f(qd == 0 ? sv.y : 0u);
    float2 a2 = bf2f(qd == 0 ? sv.z : 0u);
    float2 a3 = bf2f(qd == 0 ? sv.w : 0u);

    for (int base = beg; base < end; base += 16) {
        int mm = end - base;
        if (mm > 16) mm = 16;
        int e_nxt = (base + 16 + sub < end) ? (int)esrc[base + 16 + sub] : 0;
        int u0, u1, u2, u3;
        float w0, w1, w2, w3;
        {
            int ei = qd;
            int ix = ei < mm ? ei : mm - 1;
            u0 = __shfl(e_cur, ix, 16);
            w0 = ei < mm ? 1.f : 0.f;
        }
        {
            int ei = 4 + qd;
            int ix = ei < mm ? ei : mm - 1;
            u1 = __shfl(e_cur, ix, 16);
            w1 = ei < mm ? 1.f : 0.f;
        }
        {
            int ei = 8 + qd;
            int ix = ei < mm ? ei : mm - 1;
            u2 = __shfl(e_cur, ix, 16);
            w2 = ei < mm ? 1.f : 0.f;
        }
        {
            int ei = 12 + qd;
            int ix = ei < mm ? ei : mm - 1;
            u3 = __shfl(e_cur, ix, 16);
            w3 = ei < mm ? 1.f : 0.f;
        }
        uint4 g0 = *(const uint4*)&hsp[(size_t)u0 * 16 + qe * 4];
        uint4 g1 = *(const uint4*)&hsp[(size_t)u1 * 16 + qe * 4];
        uint4 g2 = *(const uint4*)&hsp[(size_t)u2 * 16 + qe * 4];
        uint4 g3 = *(const uint4*)&hsp[(size_t)u3 * 16 + qe * 4];
        float2 v;
        v = bf2f(g0.x); a0.x = fmaf(v.x, w0, a0.x); a0.y = fmaf(v.y, w0, a0.y);
        v = bf2f(g0.y); a1.x = fmaf(v.x, w0, a1.x); a1.y = fmaf(v.y, w0, a1.y);
        v = bf2f(g0.z); a2.x = fmaf(v.x, w0, a2.x); a2.y = fmaf(v.y, w0, a2.y);
        v = bf2f(g0.w); a3.x = fmaf(v.x, w0, a3.x); a3.y = fmaf(v.y, w0, a3.y);
        v = bf2f(g1.x); a0.x = fmaf(v.x, w1, a0.x); a0.y = fmaf(v.y, w1, a0.y);
        v = bf2f(g1.y); a1.x = fmaf(v.x, w1, a1.x); a1.y = fmaf(v.y, w1, a1.y);
        v = bf2f(g1.z); a2.x = fmaf(v.x, w1, a2.x); a2.y = fmaf(v.y, w1, a2.y);
        v = bf2f(g1.w); a3.x = fmaf(v.x, w1, a3.x); a3.y = fmaf(v.y, w1, a3.y);
        v = bf2f(g2.x); a0.x = fmaf(v.x, w2, a0.x); a0.y = fmaf(v.y, w2, a0.y);
        v = bf2f(g2.y); a1.x = fmaf(v.x, w2, a1.x); a1.y = fmaf(v.y, w2, a1.y);
        v = bf2f(g2.z); a2.x = fmaf(v.x, w2, a2.x); a2.y = fmaf(v.y, w2, a2.y);
        v = bf2f(g2.w); a3.x = fmaf(v.x, w2, a3.x); a3.y = fmaf(v.y, w2, a3.y);
        v = bf2f(g3.x); a0.x = fmaf(v.x, w3, a0.x); a0.y = fmaf(v.y, w3, a0.y);
        v = bf2f(g3.y); a1.x = fmaf(v.x, w3, a1.x); a1.y = fmaf(v.y, w3, a1.y);
        v = bf2f(g3.z); a2.x = fmaf(v.x, w3, a2.x); a2.y = fmaf(v.y, w3, a2.y);
        v = bf2f(g3.w); a3.x = fmaf(v.x, w3, a3.x); a3.y = fmaf(v.y, w3, a3.y);
        e_cur = e_nxt;
    }

    // combine edge slots: lanes {qe, qe+4, qe+8, qe+12} hold same columns
    a0.x += __shfl_xor(a0.x, 4, 16); a0.x += __shfl_xor(a0.x, 8, 16);
    a0.y += __shfl_xor(a0.y, 4, 16); a0.y += __shfl_xor(a0.y, 8, 16);
    a1.x += __shfl_xor(a1.x, 4, 16); a1.x += __shfl_xor(a1.x, 8, 16);
    a1.y += __shfl_xor(a1.y, 4, 16); a1.y += __shfl_xor(a1.y, 8, 16);
    a2.x += __shfl_xor(a2.x, 4, 16); a2.x += __shfl_xor(a2.x, 8, 16);
    a2.y += __shfl_xor(a2.y, 4, 16); a2.y += __shfl_xor(a2.y, 8, 16);
    a3.x += __shfl_xor(a3.x, 4, 16); a3.x += __shfl_xor(a3.x, 8, 16);
    a3.y += __shfl_xor(a3.y, 4, 16); a3.y += __shfl_xor(a3.y, 8, 16);

    if (qd == 0) {
        float4 r0, r1;
        r0.x = fmaf(a0.x, sc, bA.x);
        r0.y = fmaf(a0.y, sc, bA.y);
        r0.z = fmaf(a1.x, sc, bA.z);
        r0.w = fmaf(a1.y, sc, bA.w);
        r1.x = fmaf(a2.x, sc, bB.x);
        r1.y = fmaf(a2.y, sc, bB.y);
        r1.z = fmaf(a3.x, sc, bB.z);
        r1.w = fmaf(a3.y, sc, bB.w);
        float* op = &out[(size_t)node * D + p * 32 + qe * 8];
        *(float4*)op = r0;
        *(float4*)(op + 4) = r1;
        if (mode == 0) {
            // per-group exclusive LDS accumulation (no atomics needed)
            lsS[grp][qe * 8 + 0] += r0.x; lsQ[grp][qe * 8 + 0] += r0.x * r0.x;
            lsS[grp][qe * 8 + 1] += r0.y; lsQ[grp][qe * 8 + 1] += r0.y * r0.y;
            lsS[grp][qe * 8 + 2] += r0.z; lsQ[grp][qe * 8 + 2] += r0.z * r0.z;
            lsS[grp][qe * 8 + 3] += r0.w; lsQ[grp][qe * 8 + 3] += r0.w * r0.w;
            lsS[grp][qe * 8 + 4] += r1.x; lsQ[grp][qe * 8 + 4] += r1.x * r1.x;
            lsS[grp][qe * 8 + 5] += r1.y; lsQ[grp][qe * 8 + 5] += r1.y * r1.y;
            lsS[grp][qe * 8 + 6] += r1.z; lsQ[grp][qe * 8 + 6] += r1.z * r1.z;
            lsS[grp][qe * 8 + 7] += r1.w; lsQ[grp][qe * 8 + 7] += r1.w * r1.w;
        }
    }
}

__global__ __launch_bounds__(256) void k_agg(
    const unsigned* __restrict__ hs, const int* __restrict__ row_ptr,
    const unsigned short* __restrict__ esrc, const float* __restrict__ dinv,
    const unsigned short* __restrict__ perm,
    const float* __restrict__ bias, float* __restrict__ out,
    float* __restrict__ stats4, int n, int mode) {
    __shared__ float lsS[16][32];
    __shared__ float lsQ[16][32];
    int t = threadIdx.x;
    int grp = t >> 4, sub = t & 15;
    int qd = sub >> 2;   // edge slot within quad-batch (0..3)
    int qe = sub & 3;    // 16B chunk within the 64B slice (0..3)
    int bid = blockIdx.x;
    int p = (bid >> 1) & 3;                      // XCD pair {2p,2p+1} owns pass p
    int nblk = (bid >> 3) * 2 + (bid & 1);       // node-block index within pass
    const unsigned* hsp = hs + (size_t)p * n * 16;  // this pass's contiguous slice

    // zero LDS stats accumulators
    lsS[t >> 5][t & 31] = 0.f;
    lsS[(t >> 5) + 8][t & 31] = 0.f;
    lsQ[t >> 5][t & 31] = 0.f;
    lsQ[(t >> 5) + 8][t & 31] = 0.f;
    __syncthreads();

    // bias for this lane's 8 float cols (cols p*32 + qe*8 .. +7)
    float4 bA = *(const float4*)&bias[p * 32 + qe * 8];
    float4 bB = *(const float4*)&bias[p * 32 + qe * 8 + 4];

    int j0 = nblk * 32 + grp * 2;
    int pm[2];
    pm[0] = (int)perm[j0 < n ? j0 : n - 1];
    pm[1] = (int)perm[j0 + 1 < n ? j0 + 1 : n - 1];
    int rpB[2], rpE[2];
    #pragma unroll
    for (int k = 0; k < 2; k++) {
        rpB[k] = row_ptr[pm[k]];
        rpE[k] = row_ptr[pm[k] + 1];
    }

    // hoisted prefetch: both nodes' first esrc batch, self slice, dinv issued
    // together -> one amortized wait
    int eC[2];
    uint4 svC[2];
    float dvC[2];
    #pragma unroll
    for (int k = 0; k < 2; k++) {
        eC[k] = (rpB[k] + sub < rpE[k]) ? (int)esrc[rpB[k] + sub] : 0;
        svC[k] = *(const uint4*)&hsp[(size_t)pm[k] * 16 + qe * 4];
        dvC[k] = dinv[pm[k]];
    }

    #pragma unroll
    for (int ni = 0; ni < 2; ni++) {
        if (j0 + ni >= n) break;
        agg_node_w(hsp, esrc, out, lsS, lsQ, pm[ni], rpB[ni], rpE[ni], eC[ni],
                   svC[ni], dvC[ni], bA, bB, grp, sub, qd, qe, p, mode);
    }

    if (mode == 0) {
        __syncthreads();
        if (t < 32) {
            float a = 0.f, c = 0.f;
            for (int g = 0; g < 16; g++) {
                a += lsS[g][t];
                c += lsQ[g][t];
            }
            float* sbuf = stats4 + ((bid >> 2) & 3) * 256;
            atomicAdd(&sbuf[p * 32 + t], a);
            atomicAdd(&sbuf[128 + p * 32 + t], c);
        }
    }
}

// ---------------- row L2 normalize ----------------

__global__ __launch_bounds__(256) void k_l2norm(const float* __restrict__ h,
                                                float* __restrict__ out, int n) {
    int node = blockIdx.x * 4 + (threadIdx.x >> 6);
    if (node >= n) return;
    int lane = threadIdx.x & 63;
    float2 v = *(const float2*)&h[(size_t)node * D + lane * 2];
    float pw = v.x * v.x + v.y * v.y;
    #pragma unroll
    for (int off = 32; off > 0; off >>= 1) pw += __shfl_xor(pw, off, 64);
    float sc = 1.0f / fmaxf(sqrtf(pw), 1e-12f);
    float2 r;
    r.x = v.x * sc;
    r.y = v.y * sc;
    *(float2*)&out[(size_t)node * D + lane * 2] = r;
}

// ---------------- launch ----------------

extern "C" void kernel_launch(void* const* d_in, const int* in_sizes, int n_in,
                              void* d_out, int out_size, void* d_ws, size_t ws_size,
                              hipStream_t stream) {
    const float* x  = (const float*)d_in[0];
    const int*   ei = (const int*)d_in[1];
    const float* W1 = (const float*)d_in[2];
    const float* b1 = (const float*)d_in[3];
    const float* W2 = (const float*)d_in[4];
    const float* b2 = (const float*)d_in[5];
    const float* W3 = (const float*)d_in[6];
    const float* b3 = (const float*)d_in[7];
    const float* g1 = (const float*)d_in[8];
    const float* be1 = (const float*)d_in[9];
    const float* g2 = (const float*)d_in[10];
    const float* be2 = (const float*)d_in[11];

    const int N = in_sizes[0] / D;
    const int E = in_sizes[1] / 2;
    const int* src = ei;
    const int* dst = ei + E;
    const float invN = 1.0f / (float)N;

    // workspace carve
    float* Y       = (float*)d_ws;                              // N*D fp32
    unsigned short* hs = (unsigned short*)(Y + (size_t)N * D);  // N*D bf16 (slice-major)
    float* dinv    = (float*)(hs + (size_t)N * D);              // N
    float* statsA  = dinv + N;                                  // 1024
    float* statsB  = statsA + 1024;                             // 1024
    unsigned short* wt = (unsigned short*)(statsB + 1024);      // 3*16384 bf16
    int*   cnt     = (int*)(wt + 3 * 16384);                    // N
    int*   row_ptr = cnt + N;                                   // N+1
    int*   cursor  = row_ptr + N + 1;                           // N
    int*   bsum    = cursor + N;                                // 256
    unsigned short* perm = (unsigned short*)(bsum + 256);       // N u16
    unsigned short* esrc = perm + ((N + 1) & ~1);               // E u16

    const int TB = 256;
    const int gE = (E + TB - 1) / TB;
    const int NB = (N + 255) / 256;
    const int gGemm = (N + 63) / 64;
    dim3 gFill(896);   // 112 blocks x 8 XCD-pinned ranges (bid&7 = XCD = range)
    // agg grid: 32 nodes/block, node-blocks padded to even so grid % 8 == 0
    const int gx = (N + 31) / 32;
    const int gxp = (gx + 1) & ~1;
    dim3 gAgg(gxp * 4);
    const int gNode = (N + 3) / 4;

    // W precompute (+cnt zero) + CSR build (+window-256 degree sort in scan3)
    k_prepw<<<3 + NB, TB, 0, stream>>>(W1, W2, W3, wt, cnt, N);
    k_count<<<gE, TB, 0, stream>>>(dst, E, cnt);
    k_scan1<<<NB, TB, 0, stream>>>(cnt, N, bsum);
    k_scan3<<<NB, TB, 0, stream>>>(cnt, bsum, N, E, row_ptr, cursor, dinv, perm);
    k_fill<<<gFill, TB, 0, stream>>>(src, dst, E, cursor, esrc, N);

    // layer 1 (gemm1 zeroes statsA; agg1 accumulates statsA)
    k_gemm<<<gGemm, TB, 0, stream>>>(x, wt, dinv, nullptr, nullptr, nullptr, statsA,
                                     (unsigned*)hs, N, invN);
    k_agg<<<gAgg, TB, 0, stream>>>((const unsigned*)hs, row_ptr, esrc, dinv, perm, b1,
                                   Y, statsA, N, 0);

    // layer 2 (gemm2 finalizes BN1 from statsA, zeroes statsB)
    k_gemm<<<gGemm, TB, 0, stream>>>(Y, wt + 16384, dinv, statsA, g1, be1, statsB,
                                     (unsigned*)hs, N, invN);
    k_agg<<<gAgg, TB, 0, stream>>>((const unsigned*)hs, row_ptr, esrc, dinv, perm, b2,
                                   Y, statsB, N, 0);

    // layer 3 (gemm3 finalizes BN2 from statsB) + normalize
    k_gemm<<<gGemm, TB, 0, stream>>>(Y, wt + 32768, dinv, statsB, g2, be2, nullptr,
                                     (unsigned*)hs, N, invN);
    k_agg<<<gAgg, TB, 0, stream>>>((const unsigned*)hs, row_ptr, esrc, dinv, perm, b3,
                                   Y, nullptr, N, 1);
    k_l2norm<<<gNode, TB, 0, stream>>>(Y, (float*)d_out, N);
}

// Round 14
// 327.511 us; speedup vs baseline: 1.0334x; 1.0334x over previous
//
#include <hip/hip_runtime.h>
#include <hip/hip_bf16.h>

#define D 128

typedef __bf16 bf16x8 __attribute__((ext_vector_type(8)));
typedef float floatx4 __attribute__((ext_vector_type(4)));

// ---------------- CSR build ----------------

__global__ void k_count(const int* __restrict__ dst, int E, int* __restrict__ cnt) {
    int e = blockIdx.x * blockDim.x + threadIdx.x;
    if (e < E) atomicAdd(&cnt[dst[e]], 1);
}

__global__ __launch_bounds__(256) void k_scan1(const int* __restrict__ cnt, int n,
                                               int* __restrict__ bsum) {
    int i = blockIdx.x * 256 + threadIdx.x;
    int x = (i < n) ? cnt[i] : 0;
    #pragma unroll
    for (int off = 32; off > 0; off >>= 1) x += __shfl_xor(x, off, 64);
    __shared__ int ws[4];
    if ((threadIdx.x & 63) == 0) ws[threadIdx.x >> 6] = x;
    __syncthreads();
    if (threadIdx.x == 0) bsum[blockIdx.x] = ws[0] + ws[1] + ws[2] + ws[3];
}

// scan3 with scan2 folded in: each block computes its own base offset by
// summing bsum[0..bid) (NB<=256 elements, L2-hot) -> one fewer dispatch.
__global__ __launch_bounds__(256) void k_scan3(const int* __restrict__ cnt,
                                               const int* __restrict__ bsum, int n, int E,
                                               int* __restrict__ row_ptr, int* __restrict__ cursor,
                                               float* __restrict__ dinv) {
    __shared__ int ws[4];
    int t = threadIdx.x;
    int lane = t & 63, wid = t >> 6;
    // block base = sum of bsum[0..bid)
    int xb = 0;
    for (int j = t; j < blockIdx.x; j += 256) xb += bsum[j];
    #pragma unroll
    for (int off = 32; off > 0; off >>= 1) xb += __shfl_xor(xb, off, 64);
    if (lane == 0) ws[wid] = xb;
    __syncthreads();
    int o = ws[0] + ws[1] + ws[2] + ws[3];
    __syncthreads();
    // per-element prefix within block
    int i = blockIdx.x * 256 + t;
    int x = (i < n) ? cnt[i] : 0;
    int incl = x;
    #pragma unroll
    for (int off = 1; off < 64; off <<= 1) {
        int y = __shfl_up(incl, off, 64);
        if (lane >= off) incl += y;
    }
    if (lane == 63) ws[wid] = incl;
    __syncthreads();
    for (int w = 0; w < wid; w++) o += ws[w];
    if (i < n) {
        int excl = o + incl - x;
        row_ptr[i] = excl;
        cursor[i] = excl;
        dinv[i] = rsqrtf((float)(x + 1));  // +1 self loop
    }
    if (blockIdx.x == 0 && t == 0) row_ptr[n] = E;
}

// XCD-pinned range fill: range = bid & 7 = XCD. Each XCD scans all E but keeps
// only dst in its N/8 range -> esrc window (~200KB) + cursor slice live in ONE
// L2, written back once; atomics XCD-local. (Single-pass variant had 25x write
// amplification: 41MB HBM writes for 1.6MB payload.)
__global__ __launch_bounds__(256) void k_fill(const int* __restrict__ src,
                                              const int* __restrict__ dst, int E,
                                              int* __restrict__ cursor,
                                              unsigned short* __restrict__ esrc, int n) {
    int range = blockIdx.x & 7;          // = XCD
    int rb = blockIdx.x >> 3;            // block index within range
    int nb = gridDim.x >> 3;             // blocks per range
    int rs = (n + 7) >> 3;
    int lo = range * rs, hi = lo + rs;
    int step = nb * 256;
    for (int e = rb * 256 + threadIdx.x; e < E; e += step) {
        int d = dst[e];
        int s = src[e];
        if (d >= lo && d < hi) {
            int p = atomicAdd(&cursor[d], 1);
            esrc[p] = (unsigned short)s;
        }
    }
}

// ---------------- W transpose+bf16 precompute (+ cnt zeroing folded in) ----------------
// blocks 0..2: Wt[n][k] = bf16(W[k][n]); blocks 3..: zero cnt (saves a memset dispatch)

__global__ __launch_bounds__(256) void k_prepw(const float* __restrict__ W1,
                                               const float* __restrict__ W2,
                                               const float* __restrict__ W3,
                                               unsigned short* __restrict__ Wt,
                                               int* __restrict__ cnt, int n) {
    int b = blockIdx.x;
    if (b < 3) {
        const float* W = (b == 0) ? W1 : (b == 1) ? W2 : W3;
        unsigned short* o = Wt + b * 16384;
        for (int i = threadIdx.x; i < 16384; i += 256) {
            int k = i >> 7, nn = i & 127;
            __hip_bfloat16 h = __float2bfloat16(W[i]);
            o[nn * 128 + k] = *(unsigned short*)&h;
        }
    } else {
        int i = (b - 3) * 256 + threadIdx.x;
        if (i < n) cnt[i] = 0;
    }
}

// ---------------- MFMA GEMM: hs = bf16( relu_bn(X[m]) @ W * dinv[m] ) ----------
// hs is SLICE-MAJOR: hs_u32[(p * N + node) * 16 + c], p = col-pass 0..3, c 0..15.
// Prologue: finalize BN coefs from 4-way-split raw sums (stats_in), zero next stats buf.

__global__ __launch_bounds__(256) void k_gemm(
    const float* __restrict__ X, const unsigned short* __restrict__ Wt,
    const float* __restrict__ scale, const float* __restrict__ stats_in,
    const float* __restrict__ gamma, const float* __restrict__ beta,
    float* __restrict__ stats_zero,
    unsigned* __restrict__ hs, int n, float invN) {
    __shared__ unsigned short Wl[128 * 128];
    __shared__ float bnl[256];
    int t = threadIdx.x;
    if (stats_in && t < 128) {
        float s = stats_in[t] + stats_in[256 + t] + stats_in[512 + t] + stats_in[768 + t];
        float q = stats_in[128 + t] + stats_in[384 + t] + stats_in[640 + t] + stats_in[896 + t];
        float mean = s * invN;
        float var = q * invN - mean * mean;
        float a = gamma[t] * rsqrtf(var + 1e-5f);
        bnl[t] = a;
        bnl[128 + t] = beta[t] - mean * a;
    }
    if (stats_zero && blockIdx.x == 0) {
        stats_zero[t] = 0.f;
        stats_zero[256 + t] = 0.f;
        stats_zero[512 + t] = 0.f;
        stats_zero[768 + t] = 0.f;
    }
    // stage Wt: 2048 uint4; chunk lc of row nn stored at physical chunk lc^(nn&15)
    {
        const uint4* wg = (const uint4*)Wt;
        uint4* wl4 = (uint4*)Wl;
        #pragma unroll
        for (int j = 0; j < 8; j++) {
            int idx = j * 256 + t;
            int nn = idx >> 4, lc = idx & 15;
            wl4[nn * 16 + (lc ^ (nn & 15))] = wg[idx];
        }
    }
    __syncthreads();

    int l = t & 63, w = t >> 6;
    int lm = l & 15, quad = l >> 4;
    int m = blockIdx.x * 64 + w * 16 + lm;
    int rm = (m < n) ? m : (n - 1);
    const float* xrow = X + (size_t)rm * D;

    floatx4 acc[8];
    #pragma unroll
    for (int nt = 0; nt < 8; nt++) acc[nt] = (floatx4){0.f, 0.f, 0.f, 0.f};

    #pragma unroll
    for (int ks = 0; ks < 4; ks++) {
        int k0 = ks * 32 + quad * 8;
        float4 xa = *(const float4*)(xrow + k0);
        float4 xb = *(const float4*)(xrow + k0 + 4);
        if (stats_in) {
            float4 a0 = *(const float4*)&bnl[k0];
            float4 a1 = *(const float4*)&bnl[k0 + 4];
            float4 c0 = *(const float4*)&bnl[128 + k0];
            float4 c1 = *(const float4*)&bnl[128 + k0 + 4];
            xa.x = fmaxf(xa.x * a0.x + c0.x, 0.f);
            xa.y = fmaxf(xa.y * a0.y + c0.y, 0.f);
            xa.z = fmaxf(xa.z * a0.z + c0.z, 0.f);
            xa.w = fmaxf(xa.w * a0.w + c0.w, 0.f);
            xb.x = fmaxf(xb.x * a1.x + c1.x, 0.f);
            xb.y = fmaxf(xb.y * a1.y + c1.y, 0.f);
            xb.z = fmaxf(xb.z * a1.z + c1.z, 0.f);
            xb.w = fmaxf(xb.w * a1.w + c1.w, 0.f);
        }
        bf16x8 xf;
        xf[0] = (__bf16)xa.x; xf[1] = (__bf16)xa.y;
        xf[2] = (__bf16)xa.z; xf[3] = (__bf16)xa.w;
        xf[4] = (__bf16)xb.x; xf[5] = (__bf16)xb.y;
        xf[6] = (__bf16)xb.z; xf[7] = (__bf16)xb.w;
        int pc = (ks * 4 + quad) ^ lm;
        #pragma unroll
        for (int nt = 0; nt < 8; nt++) {
            const bf16x8 wf = *(const bf16x8*)&Wl[(nt * 16 + lm) * 128 + pc * 8];
            acc[nt] = __builtin_amdgcn_mfma_f32_16x16x32_bf16(wf, xf, acc[nt], 0, 0, 0);
        }
    }

    float s = scale[rm];
    if (m < n) {
        #pragma unroll
        for (int nt = 0; nt < 8; nt++) {
            __hip_bfloat16 h0 = __float2bfloat16(acc[nt][0] * s);
            __hip_bfloat16 h1 = __float2bfloat16(acc[nt][1] * s);
            __hip_bfloat16 h2 = __float2bfloat16(acc[nt][2] * s);
            __hip_bfloat16 h3 = __float2bfloat16(acc[nt][3] * s);
            uint2 uu;
            uu.x = (unsigned)*(unsigned short*)&h0 | ((unsigned)*(unsigned short*)&h1 << 16);
            uu.y = (unsigned)*(unsigned short*)&h2 | ((unsigned)*(unsigned short*)&h3 << 16);
            // slice-major: pass = nt>>1, within-pass u32 col = (nt&1)*8 + quad*2
            *(uint2*)&hs[((size_t)(nt >> 1) * n + m) * 16 + (nt & 1) * 8 + quad * 2] = uu;
        }
    }
}

// ---------------- Column-blocked aggregation (4 passes x 64B slice) ----------
// Final proven structure: slice-major hs, XCD-pinned static 1D grid, wide
// dwordx4 gathers (4 lanes/edge, one vmcnt wait per 16-edge batch), no
// barriers/queues in loop, 2 nodes per 16-lane group (32/block) for tail-round
// fill, natural node order (degree-sorting refuted 3 ways: global sort doubles
// FETCH via scattered esrc, window sort adds a perm dependency level — the
// binding cost is the dependent-wait chain, not gather-iteration count).
// mode 0: BN stats into per-group LDS, flushed once at end.

__device__ inline float2 bf2f(unsigned u) {
    union { unsigned i; float f; } lo, hi;
    lo.i = u << 16;
    hi.i = u & 0xffff0000u;
    float2 r; r.x = lo.f; r.y = hi.f; return r;
}

__device__ __forceinline__ void agg_node_w(
    const unsigned* __restrict__ hsp, const unsigned short* __restrict__ esrc,
    float* __restrict__ out, float (*lsS)[32], float (*lsQ)[32],
    int node, int beg, int end, int e_cur, uint4 sv, float sc,
    float4 bA, float4 bB, int grp, int sub, int qd, int qe, int p, int mode) {
    // self contributes only in edge-slot 0 (summed once after xor-reduce)
    float2 a0 = bf2f(qd == 0 ? sv.x : 0u);
    float2 a1 = bf2f(qd == 0 ? sv.y : 0u);
    float2 a2 = bf2f(qd == 0 ? sv.z : 0u);
    float2 a3 = bf2f(qd == 0 ? sv.w : 0u);

    for (int base = beg; base < end; base += 16) {
        int mm = end - base;
        if (mm > 16) mm = 16;
        int e_nxt = (base + 16 + sub < end) ? (int)esrc[base + 16 + sub] : 0;
        int u0, u1, u2, u3;
        float w0, w1, w2, w3;
        {
            int ei = qd;
            int ix = ei < mm ? ei : mm - 1;
            u0 = __shfl(e_cur, ix, 16);
            w0 = ei < mm ? 1.f : 0.f;
        }
        {
            int ei = 4 + qd;
            int ix = ei < mm ? ei : mm - 1;
            u1 = __shfl(e_cur, ix, 16);
            w1 = ei < mm ? 1.f : 0.f;
        }
        {
            int ei = 8 + qd;
            int ix = ei < mm ? ei : mm - 1;
            u2 = __shfl(e_cur, ix, 16);
            w2 = ei < mm ? 1.f : 0.f;
        }
        {
            int ei = 12 + qd;
            int ix = ei < mm ? ei : mm - 1;
            u3 = __shfl(e_cur, ix, 16);
            w3 = ei < mm ? 1.f : 0.f;
        }
        uint4 g0 = *(const uint4*)&hsp[(size_t)u0 * 16 + qe * 4];
        uint4 g1 = *(const uint4*)&hsp[(size_t)u1 * 16 + qe * 4];
        uint4 g2 = *(const uint4*)&hsp[(size_t)u2 * 16 + qe * 4];
        uint4 g3 = *(const uint4*)&hsp[(size_t)u3 * 16 + qe * 4];
        float2 v;
        v = bf2f(g0.x); a0.x = fmaf(v.x, w0, a0.x); a0.y = fmaf(v.y, w0, a0.y);
        v = bf2f(g0.y); a1.x = fmaf(v.x, w0, a1.x); a1.y = fmaf(v.y, w0, a1.y);
        v = bf2f(g0.z); a2.x = fmaf(v.x, w0, a2.x); a2.y = fmaf(v.y, w0, a2.y);
        v = bf2f(g0.w); a3.x = fmaf(v.x, w0, a3.x); a3.y = fmaf(v.y, w0, a3.y);
        v = bf2f(g1.x); a0.x = fmaf(v.x, w1, a0.x); a0.y = fmaf(v.y, w1, a0.y);
        v = bf2f(g1.y); a1.x = fmaf(v.x, w1, a1.x); a1.y = fmaf(v.y, w1, a1.y);
        v = bf2f(g1.z); a2.x = fmaf(v.x, w1, a2.x); a2.y = fmaf(v.y, w1, a2.y);
        v = bf2f(g1.w); a3.x = fmaf(v.x, w1, a3.x); a3.y = fmaf(v.y, w1, a3.y);
        v = bf2f(g2.x); a0.x = fmaf(v.x, w2, a0.x); a0.y = fmaf(v.y, w2, a0.y);
        v = bf2f(g2.y); a1.x = fmaf(v.x, w2, a1.x); a1.y = fmaf(v.y, w2, a1.y);
        v = bf2f(g2.z); a2.x = fmaf(v.x, w2, a2.x); a2.y = fmaf(v.y, w2, a2.y);
        v = bf2f(g2.w); a3.x = fmaf(v.x, w2, a3.x); a3.y = fmaf(v.y, w2, a3.y);
        v = bf2f(g3.x); a0.x = fmaf(v.x, w3, a0.x); a0.y = fmaf(v.y, w3, a0.y);
        v = bf2f(g3.y); a1.x = fmaf(v.x, w3, a1.x); a1.y = fmaf(v.y, w3, a1.y);
        v = bf2f(g3.z); a2.x = fmaf(v.x, w3, a2.x); a2.y = fmaf(v.y, w3, a2.y);
        v = bf2f(g3.w); a3.x = fmaf(v.x, w3, a3.x); a3.y = fmaf(v.y, w3, a3.y);
        e_cur = e_nxt;
    }

    // combine edge slots: lanes {qe, qe+4, qe+8, qe+12} hold same columns
    a0.x += __shfl_xor(a0.x, 4, 16); a0.x += __shfl_xor(a0.x, 8, 16);
    a0.y += __shfl_xor(a0.y, 4, 16); a0.y += __shfl_xor(a0.y, 8, 16);
    a1.x += __shfl_xor(a1.x, 4, 16); a1.x += __shfl_xor(a1.x, 8, 16);
    a1.y += __shfl_xor(a1.y, 4, 16); a1.y += __shfl_xor(a1.y, 8, 16);
    a2.x += __shfl_xor(a2.x, 4, 16); a2.x += __shfl_xor(a2.x, 8, 16);
    a2.y += __shfl_xor(a2.y, 4, 16); a2.y += __shfl_xor(a2.y, 8, 16);
    a3.x += __shfl_xor(a3.x, 4, 16); a3.x += __shfl_xor(a3.x, 8, 16);
    a3.y += __shfl_xor(a3.y, 4, 16); a3.y += __shfl_xor(a3.y, 8, 16);

    if (qd == 0) {
        float4 r0, r1;
        r0.x = fmaf(a0.x, sc, bA.x);
        r0.y = fmaf(a0.y, sc, bA.y);
        r0.z = fmaf(a1.x, sc, bA.z);
        r0.w = fmaf(a1.y, sc, bA.w);
        r1.x = fmaf(a2.x, sc, bB.x);
        r1.y = fmaf(a2.y, sc, bB.y);
        r1.z = fmaf(a3.x, sc, bB.z);
        r1.w = fmaf(a3.y, sc, bB.w);
        float* op = &out[(size_t)node * D + p * 32 + qe * 8];
        *(float4*)op = r0;
        *(float4*)(op + 4) = r1;
        if (mode == 0) {
            // per-group exclusive LDS accumulation (no atomics needed)
            lsS[grp][qe * 8 + 0] += r0.x; lsQ[grp][qe * 8 + 0] += r0.x * r0.x;
            lsS[grp][qe * 8 + 1] += r0.y; lsQ[grp][qe * 8 + 1] += r0.y * r0.y;
            lsS[grp][qe * 8 + 2] += r0.z; lsQ[grp][qe * 8 + 2] += r0.z * r0.z;
            lsS[grp][qe * 8 + 3] += r0.w; lsQ[grp][qe * 8 + 3] += r0.w * r0.w;
            lsS[grp][qe * 8 + 4] += r1.x; lsQ[grp][qe * 8 + 4] += r1.x * r1.x;
            lsS[grp][qe * 8 + 5] += r1.y; lsQ[grp][qe * 8 + 5] += r1.y * r1.y;
            lsS[grp][qe * 8 + 6] += r1.z; lsQ[grp][qe * 8 + 6] += r1.z * r1.z;
            lsS[grp][qe * 8 + 7] += r1.w; lsQ[grp][qe * 8 + 7] += r1.w * r1.w;
        }
    }
}

__global__ __launch_bounds__(256) void k_agg(
    const unsigned* __restrict__ hs, const int* __restrict__ row_ptr,
    const unsigned short* __restrict__ esrc, const float* __restrict__ dinv,
    const float* __restrict__ bias, float* __restrict__ out,
    float* __restrict__ stats4, int n, int mode) {
    __shared__ float lsS[16][32];
    __shared__ float lsQ[16][32];
    int t = threadIdx.x;
    int grp = t >> 4, sub = t & 15;
    int qd = sub >> 2;   // edge slot within quad-batch (0..3)
    int qe = sub & 3;    // 16B chunk within the 64B slice (0..3)
    int bid = blockIdx.x;
    int p = (bid >> 1) & 3;                      // XCD pair {2p,2p+1} owns pass p
    int nblk = (bid >> 3) * 2 + (bid & 1);       // node-block index within pass
    const unsigned* hsp = hs + (size_t)p * n * 16;  // this pass's contiguous slice

    // zero LDS stats accumulators
    lsS[t >> 5][t & 31] = 0.f;
    lsS[(t >> 5) + 8][t & 31] = 0.f;
    lsQ[t >> 5][t & 31] = 0.f;
    lsQ[(t >> 5) + 8][t & 31] = 0.f;
    __syncthreads();

    // bias for this lane's 8 float cols (cols p*32 + qe*8 .. +7)
    float4 bA = *(const float4*)&bias[p * 32 + qe * 8];
    float4 bB = *(const float4*)&bias[p * 32 + qe * 8 + 4];

    int node0 = nblk * 32 + grp * 2;
    int rp[3];
    #pragma unroll
    for (int k = 0; k < 3; k++) {
        int ik = node0 + k;
        if (ik > n) ik = n;
        rp[k] = row_ptr[ik];
    }

    // hoisted prefetch: both nodes' first esrc batch, self slice, dinv issued
    // together -> one amortized wait
    int eC[2];
    uint4 svC[2];
    float dvC[2];
    #pragma unroll
    for (int k = 0; k < 2; k++) {
        int nk = node0 + k;
        int ck = nk < n ? nk : n - 1;
        eC[k] = (rp[k] + sub < rp[k + 1]) ? (int)esrc[rp[k] + sub] : 0;
        svC[k] = *(const uint4*)&hsp[(size_t)ck * 16 + qe * 4];
        dvC[k] = dinv[ck];
    }

    #pragma unroll
    for (int ni = 0; ni < 2; ni++) {
        int node = node0 + ni;
        if (node >= n) break;
        agg_node_w(hsp, esrc, out, lsS, lsQ, node, rp[ni], rp[ni + 1], eC[ni],
                   svC[ni], dvC[ni], bA, bB, grp, sub, qd, qe, p, mode);
    }

    if (mode == 0) {
        __syncthreads();
        if (t < 32) {
            float a = 0.f, c = 0.f;
            for (int g = 0; g < 16; g++) {
                a += lsS[g][t];
                c += lsQ[g][t];
            }
            float* sbuf = stats4 + ((bid >> 2) & 3) * 256;
            atomicAdd(&sbuf[p * 32 + t], a);
            atomicAdd(&sbuf[128 + p * 32 + t], c);
        }
    }
}

// ---------------- row L2 normalize ----------------

__global__ __launch_bounds__(256) void k_l2norm(const float* __restrict__ h,
                                                float* __restrict__ out, int n) {
    int node = blockIdx.x * 4 + (threadIdx.x >> 6);
    if (node >= n) return;
    int lane = threadIdx.x & 63;
    float2 v = *(const float2*)&h[(size_t)node * D + lane * 2];
    float pw = v.x * v.x + v.y * v.y;
    #pragma unroll
    for (int off = 32; off > 0; off >>= 1) pw += __shfl_xor(pw, off, 64);
    float sc = 1.0f / fmaxf(sqrtf(pw), 1e-12f);
    float2 r;
    r.x = v.x * sc;
    r.y = v.y * sc;
    *(float2*)&out[(size_t)node * D + lane * 2] = r;
}

// ---------------- launch ----------------

extern "C" void kernel_launch(void* const* d_in, const int* in_sizes, int n_in,
                              void* d_out, int out_size, void* d_ws, size_t ws_size,
                              hipStream_t stream) {
    const float* x  = (const float*)d_in[0];
    const int*   ei = (const int*)d_in[1];
    const float* W1 = (const float*)d_in[2];
    const float* b1 = (const float*)d_in[3];
    const float* W2 = (const float*)d_in[4];
    const float* b2 = (const float*)d_in[5];
    const float* W3 = (const float*)d_in[6];
    const float* b3 = (const float*)d_in[7];
    const float* g1 = (const float*)d_in[8];
    const float* be1 = (const float*)d_in[9];
    const float* g2 = (const float*)d_in[10];
    const float* be2 = (const float*)d_in[11];

    const int N = in_sizes[0] / D;
    const int E = in_sizes[1] / 2;
    const int* src = ei;
    const int* dst = ei + E;
    const float invN = 1.0f / (float)N;

    // workspace carve
    float* Y       = (float*)d_ws;                              // N*D fp32
    unsigned short* hs = (unsigned short*)(Y + (size_t)N * D);  // N*D bf16 (slice-major)
    float* dinv    = (float*)(hs + (size_t)N * D);              // N
    float* statsA  = dinv + N;                                  // 1024
    float* statsB  = statsA + 1024;                             // 1024
    unsigned short* wt = (unsigned short*)(statsB + 1024);      // 3*16384 bf16
    int*   cnt     = (int*)(wt + 3 * 16384);                    // N
    int*   row_ptr = cnt + N;                                   // N+1
    int*   cursor  = row_ptr + N + 1;                           // N
    int*   bsum    = cursor + N;                                // 256
    unsigned short* esrc = (unsigned short*)(bsum + 256);       // E u16

    const int TB = 256;
    const int gE = (E + TB - 1) / TB;
    const int NB = (N + 255) / 256;
    const int gGemm = (N + 63) / 64;
    dim3 gFill(896);   // 112 blocks x 8 XCD-pinned ranges (bid&7 = XCD = range)
    // agg grid: 32 nodes/block, node-blocks padded to even so grid % 8 == 0
    const int gx = (N + 31) / 32;
    const int gxp = (gx + 1) & ~1;
    dim3 gAgg(gxp * 4);
    const int gNode = (N + 3) / 4;

    // W precompute (+cnt zero) + CSR build
    k_prepw<<<3 + NB, TB, 0, stream>>>(W1, W2, W3, wt, cnt, N);
    k_count<<<gE, TB, 0, stream>>>(dst, E, cnt);
    k_scan1<<<NB, TB, 0, stream>>>(cnt, N, bsum);
    k_scan3<<<NB, TB, 0, stream>>>(cnt, bsum, N, E, row_ptr, cursor, dinv);
    k_fill<<<gFill, TB, 0, stream>>>(src, dst, E, cursor, esrc, N);

    // layer 1 (gemm1 zeroes statsA; agg1 accumulates statsA)
    k_gemm<<<gGemm, TB, 0, stream>>>(x, wt, dinv, nullptr, nullptr, nullptr, statsA,
                                     (unsigned*)hs, N, invN);
    k_agg<<<gAgg, TB, 0, stream>>>((const unsigned*)hs, row_ptr, esrc, dinv, b1, Y,
                                   statsA, N, 0);

    // layer 2 (gemm2 finalizes BN1 from statsA, zeroes statsB)
    k_gemm<<<gGemm, TB, 0, stream>>>(Y, wt + 16384, dinv, statsA, g1, be1, statsB,
                                     (unsigned*)hs, N, invN);
    k_agg<<<gAgg, TB, 0, stream>>>((const unsigned*)hs, row_ptr, esrc, dinv, b2, Y,
                                   statsB, N, 0);

    // layer 3 (gemm3 finalizes BN2 from statsB) + normalize
    k_gemm<<<gGemm, TB, 0, stream>>>(Y, wt + 32768, dinv, statsB, g2, be2, nullptr,
                                     (unsigned*)hs, N, invN);
    k_agg<<<gAgg, TB, 0, stream>>>((const unsigned*)hs, row_ptr, esrc, dinv, b3, Y,
                                   nullptr, N, 1);
    k_l2norm<<<gNode, TB, 0, stream>>>(Y, (float*)d_out, N);
}